// Round 1
// baseline (279.844 us; speedup 1.0000x reference)
//
#include <hip/hip_runtime.h>
#include <math.h>

// Problem: B=64 rows, T=524288 cols, f32. loss = mean_i ||pred_i - true_i||_2.
// Memory-bound: 268 MB read / launch. Two-stage deterministic reduction.

#define B_ROWS 64
#define T_ELEMS 524288
#define CHUNKS_PER_ROW 16           // blocks per row
#define BLOCK 256

// T/4 float4 per row = 131072; per chunk = 8192 float4; per thread = 32 float4.

__global__ __launch_bounds__(BLOCK) void sdtw_stage1(
    const float4* __restrict__ yp, const float4* __restrict__ yt,
    float* __restrict__ partial)
{
    const int row   = blockIdx.x >> 4;          // / CHUNKS_PER_ROW
    const int chunk = blockIdx.x & (CHUNKS_PER_ROW - 1);
    const int T4        = T_ELEMS / 4;          // 131072
    const int per_chunk = T4 / CHUNKS_PER_ROW;  // 8192
    const size_t base = (size_t)row * T4 + (size_t)chunk * per_chunk;

    float acc = 0.0f;
#pragma unroll 4
    for (int k = 0; k < per_chunk / BLOCK; ++k) {   // 32 iterations
        size_t idx = base + (size_t)k * BLOCK + threadIdx.x;  // coalesced
        float4 a = yp[idx];
        float4 b = yt[idx];
        float dx = a.x - b.x, dy = a.y - b.y, dz = a.z - b.z, dw = a.w - b.w;
        acc += dx * dx + dy * dy + dz * dz + dw * dw;
    }

    // wave-64 shuffle reduction
    for (int off = 32; off > 0; off >>= 1)
        acc += __shfl_down(acc, off, 64);

    __shared__ float s[BLOCK / 64];
    const int lane = threadIdx.x & 63;
    const int wave = threadIdx.x >> 6;
    if (lane == 0) s[wave] = acc;
    __syncthreads();
    if (threadIdx.x == 0) {
        float r = 0.0f;
#pragma unroll
        for (int w = 0; w < BLOCK / 64; ++w) r += s[w];
        partial[blockIdx.x] = r;   // layout: row*16 + chunk
    }
}

__global__ __launch_bounds__(64) void sdtw_stage2(
    const float* __restrict__ partial, float* __restrict__ out)
{
    // one wave: thread i handles row i
    float acc = 0.0f;
#pragma unroll
    for (int k = 0; k < CHUNKS_PER_ROW; ++k)
        acc += partial[threadIdx.x * CHUNKS_PER_ROW + k];
    float norm = sqrtf(acc);
    for (int off = 32; off > 0; off >>= 1)
        norm += __shfl_down(norm, off, 64);
    if (threadIdx.x == 0)
        out[0] = norm * (1.0f / (float)B_ROWS);
}

extern "C" void kernel_launch(void* const* d_in, const int* in_sizes, int n_in,
                              void* d_out, int out_size, void* d_ws, size_t ws_size,
                              hipStream_t stream) {
    const float4* yp = (const float4*)d_in[0];
    const float4* yt = (const float4*)d_in[1];
    float* partial = (float*)d_ws;   // 1024 floats = 4 KB
    float* out = (float*)d_out;

    sdtw_stage1<<<B_ROWS * CHUNKS_PER_ROW, BLOCK, 0, stream>>>(yp, yt, partial);
    sdtw_stage2<<<1, 64, 0, stream>>>(partial, out);
}

// Round 2
// 271.323 us; speedup vs baseline: 1.0314x; 1.0314x over previous
//
#include <hip/hip_runtime.h>
#include <math.h>

// B=64 rows, T=524288 cols, f32. loss = mean_i ||pred_i - true_i||_2.
// Memory-bound: 268 MB read. R1 fix: deep memory-level parallelism —
// 16 independent float4 loads in flight per lane (VGPR was 24 -> loads
// were serialized; now explicit 8-wide batches per stream).

#define B_ROWS 64
#define T_ELEMS 524288
#define CHUNKS_PER_ROW 32           // 2048 blocks total
#define BLOCK 256

// T/4 = 131072 float4/row/stream; per chunk 4096; per thread 16 (2 batches of 8).

__global__ __launch_bounds__(BLOCK) void sdtw_stage1(
    const float4* __restrict__ yp, const float4* __restrict__ yt,
    float* __restrict__ partial)
{
    const int row   = blockIdx.x >> 5;          // / CHUNKS_PER_ROW
    const int chunk = blockIdx.x & (CHUNKS_PER_ROW - 1);
    const int T4        = T_ELEMS / 4;          // 131072
    const int per_chunk = T4 / CHUNKS_PER_ROW;  // 4096 float4
    const size_t base = (size_t)row * T4 + (size_t)chunk * per_chunk;

    float acc0 = 0.0f, acc1 = 0.0f;
#pragma unroll
    for (int b = 0; b < 2; ++b) {
        const size_t idx = base + (size_t)b * (8 * BLOCK) + threadIdx.x;
        float4 A[8], Bv[8];
#pragma unroll
        for (int i = 0; i < 8; ++i) A[i]  = yp[idx + (size_t)i * BLOCK];
#pragma unroll
        for (int i = 0; i < 8; ++i) Bv[i] = yt[idx + (size_t)i * BLOCK];
#pragma unroll
        for (int i = 0; i < 8; ++i) {
            float dx = A[i].x - Bv[i].x;
            float dy = A[i].y - Bv[i].y;
            float dz = A[i].z - Bv[i].z;
            float dw = A[i].w - Bv[i].w;
            if (i & 1) acc1 += dx * dx + dy * dy + dz * dz + dw * dw;
            else       acc0 += dx * dx + dy * dy + dz * dz + dw * dw;
        }
    }
    float acc = acc0 + acc1;

    // wave-64 shuffle reduction
    for (int off = 32; off > 0; off >>= 1)
        acc += __shfl_down(acc, off, 64);

    __shared__ float s[BLOCK / 64];
    const int lane = threadIdx.x & 63;
    const int wave = threadIdx.x >> 6;
    if (lane == 0) s[wave] = acc;
    __syncthreads();
    if (threadIdx.x == 0) {
        float r = 0.0f;
#pragma unroll
        for (int w = 0; w < BLOCK / 64; ++w) r += s[w];
        partial[blockIdx.x] = r;   // layout: row*CHUNKS_PER_ROW + chunk
    }
}

__global__ __launch_bounds__(64) void sdtw_stage2(
    const float* __restrict__ partial, float* __restrict__ out)
{
    // one wave: thread i handles row i
    float acc = 0.0f;
#pragma unroll
    for (int k = 0; k < CHUNKS_PER_ROW; ++k)
        acc += partial[threadIdx.x * CHUNKS_PER_ROW + k];
    float norm = sqrtf(acc);
    for (int off = 32; off > 0; off >>= 1)
        norm += __shfl_down(norm, off, 64);
    if (threadIdx.x == 0)
        out[0] = norm * (1.0f / (float)B_ROWS);
}

extern "C" void kernel_launch(void* const* d_in, const int* in_sizes, int n_in,
                              void* d_out, int out_size, void* d_ws, size_t ws_size,
                              hipStream_t stream) {
    const float4* yp = (const float4*)d_in[0];
    const float4* yt = (const float4*)d_in[1];
    float* partial = (float*)d_ws;   // 2048 floats = 8 KB
    float* out = (float*)d_out;

    sdtw_stage1<<<B_ROWS * CHUNKS_PER_ROW, BLOCK, 0, stream>>>(yp, yt, partial);
    sdtw_stage2<<<1, 64, 0, stream>>>(partial, out);
}

// Round 4
// 247.356 us; speedup vs baseline: 1.1313x; 1.0969x over previous
//
#include <hip/hip_runtime.h>
#include <math.h>

// B=64 rows, T=524288 cols, f32. loss = mean_i ||pred_i - true_i||_2.
// R3: nontemporal (nt) loads to avoid L3 allocation churn against the
// harness's dirty restore-resident lines. Native vector type for the
// builtin (HIP_vector_type struct is rejected).

#define B_ROWS 64
#define T_ELEMS 524288
#define CHUNKS_PER_ROW 64           // 4096 blocks total
#define BLOCK 256

typedef float f4 __attribute__((ext_vector_type(4)));

// T/4 = 131072 f4/row/input; per chunk 2048; per thread 8 per input.

__global__ __launch_bounds__(BLOCK) void sdtw_stage1(
    const f4* __restrict__ yp, const f4* __restrict__ yt,
    float* __restrict__ partial)
{
    const int row   = blockIdx.x >> 6;          // / CHUNKS_PER_ROW
    const int chunk = blockIdx.x & (CHUNKS_PER_ROW - 1);
    const int T4        = T_ELEMS / 4;          // 131072
    const int per_chunk = T4 / CHUNKS_PER_ROW;  // 2048 f4
    const size_t base = (size_t)row * T4 + (size_t)chunk * per_chunk;

    f4 A[8], Bv[8];
    const size_t idx = base + threadIdx.x;
#pragma unroll
    for (int i = 0; i < 8; ++i)
        A[i]  = __builtin_nontemporal_load(&yp[idx + (size_t)i * BLOCK]);
#pragma unroll
    for (int i = 0; i < 8; ++i)
        Bv[i] = __builtin_nontemporal_load(&yt[idx + (size_t)i * BLOCK]);

    float acc0 = 0.0f, acc1 = 0.0f;
#pragma unroll
    for (int i = 0; i < 8; ++i) {
        f4 d = A[i] - Bv[i];
        float p = d.x * d.x + d.y * d.y + d.z * d.z + d.w * d.w;
        if (i & 1) acc1 += p; else acc0 += p;
    }
    float acc = acc0 + acc1;

    // wave-64 shuffle reduction
    for (int off = 32; off > 0; off >>= 1)
        acc += __shfl_down(acc, off, 64);

    __shared__ float s[BLOCK / 64];
    const int lane = threadIdx.x & 63;
    const int wave = threadIdx.x >> 6;
    if (lane == 0) s[wave] = acc;
    __syncthreads();
    if (threadIdx.x == 0) {
        float r = 0.0f;
#pragma unroll
        for (int w = 0; w < BLOCK / 64; ++w) r += s[w];
        partial[blockIdx.x] = r;   // layout: row*CHUNKS_PER_ROW + chunk
    }
}

__global__ __launch_bounds__(64) void sdtw_stage2(
    const float* __restrict__ partial, float* __restrict__ out)
{
    // one wave: thread i handles row i
    float acc = 0.0f;
#pragma unroll
    for (int k = 0; k < CHUNKS_PER_ROW; ++k)
        acc += partial[threadIdx.x * CHUNKS_PER_ROW + k];
    float norm = sqrtf(acc);
    for (int off = 32; off > 0; off >>= 1)
        norm += __shfl_down(norm, off, 64);
    if (threadIdx.x == 0)
        out[0] = norm * (1.0f / (float)B_ROWS);
}

extern "C" void kernel_launch(void* const* d_in, const int* in_sizes, int n_in,
                              void* d_out, int out_size, void* d_ws, size_t ws_size,
                              hipStream_t stream) {
    const f4* yp = (const f4*)d_in[0];
    const f4* yt = (const f4*)d_in[1];
    float* partial = (float*)d_ws;   // 4096 floats = 16 KB
    float* out = (float*)d_out;

    sdtw_stage1<<<B_ROWS * CHUNKS_PER_ROW, BLOCK, 0, stream>>>(yp, yt, partial);
    sdtw_stage2<<<1, 64, 0, stream>>>(partial, out);
}